// Round 10
// baseline (253.736 us; speedup 1.0000x reference)
//
#include <hip/hip_runtime.h>
#include <hip/hip_bf16.h>

// Problem constants (match reference)
#define TB   128          // batch B
#define NN   512          // nodes per graph
#define INC  128          // IN_C
#define HH   32           // HID
#define KP1  100          // K1
#define KP2  10           // K2
#define OC   10           // OUT_C
#define EPER 8192         // edges per graph
#define NT   (TB*NN)      // 65536 total nodes
#define ET   (TB*EPER)    // 1048576 total edges
#define ZTR  264          // gram ZT rows: 232 Z-cols + 32 zero pad (partial MFMA tiles)
#define ZTS  40           // ZT row stride in u16 (80 B, 16B-aligned for ds_read_b128)
#define XTS  136          // xw row stride in u16 (272 B, 16B-aligned)
#define CSZ  (KP1*232)    // per-partial C tile floats (23200)

typedef unsigned int  u32;
typedef unsigned short u16;
typedef __attribute__((ext_vector_type(8))) short bf16x8;   // 8 bf16 = 4 VGPR (MFMA A/B frag)
typedef __attribute__((ext_vector_type(16))) float f32x16;  // MFMA C/D frag

// bf16 helpers (RNE encode; exact decode)
__device__ __forceinline__ u32 bfr(float f) {
    u32 b = __float_as_uint(f);
    return (b + 0x7fffu + ((b >> 16) & 1u)) >> 16;
}
__device__ __forceinline__ u32 pk2(float a, float b) { return bfr(a) | (bfr(b) << 16); }
__device__ __forceinline__ float blo(u32 u) { return __uint_as_float(u << 16); }
__device__ __forceinline__ float bhi(u32 u) { return __uint_as_float(u & 0xffff0000u); }

// ==== k_pre: sort (blocks 0..127) ∥ xw (blocks 128..255), one launch ====
__global__ __launch_bounds__(1024) void k_pre(const int* __restrict__ ei,
                                              int* __restrict__ cnt_src, int* __restrict__ cnt_dst,
                                              int* __restrict__ off_src, int* __restrict__ off_dst,
                                              u16* __restrict__ srt_dst, u16* __restrict__ srt_src,
                                              float* __restrict__ dis, float* __restrict__ aux,
                                              const float* __restrict__ x, const float* __restrict__ W,
                                              u16* __restrict__ xwb, float* __restrict__ out) {
    __shared__ __align__(16) u16 sX[512 * XTS];   // 139.3 KB (xw staging; sort overlays first 40 KB)
    __shared__ __align__(16) u16 sW[32 * XTS];    // 8.7 KB
    int tid = threadIdx.x, b = blockIdx.x;
    if (b < TB) {
        // -------- sort role --------
        int* hs = (int*)sX;
        int* hd = hs + NN;
        int* ps = hd + NN;
        int* pd = ps + NN;
        u16* sdl = (u16*)(pd + NN);
        u16* ssl = sdl + EPER;
        int g = b, goff = g * NN;
        if (tid == 0) aux[g] = 0.f;               // den1 accumulator zero
        if (g == 0 && tid == 0) out[1280] = 0.f;  // loss accumulator zero
        if (tid < NN) { hs[tid] = 0; hd[tid] = 0; }
        __syncthreads();
        const int* es = ei + (size_t)g * EPER;
        const int* ed = ei + ET + (size_t)g * EPER;
        for (int e = tid; e < EPER; e += 1024) {
            atomicAdd(&hs[es[e] - goff], 1);
            atomicAdd(&hd[ed[e] - goff], 1);
        }
        __syncthreads();
        int vs = 0, vd = 0;
        if (tid < NN) { vs = hs[tid]; vd = hd[tid]; ps[tid] = vs; pd[tid] = vd; }
        __syncthreads();
        for (int off = 1; off < NN; off <<= 1) {
            int xa = 0, xb = 0;
            if (tid < NN) {
                xa = ps[tid]; xb = pd[tid];
                if (tid >= off) { xa += ps[tid - off]; xb += pd[tid - off]; }
            }
            __syncthreads();
            if (tid < NN) { ps[tid] = xa; pd[tid] = xb; }
            __syncthreads();
        }
        int eso = 0, edo = 0;
        if (tid < NN) {
            eso = ps[tid] - vs; edo = pd[tid] - vd;
            cnt_src[goff + tid] = vs;  cnt_dst[goff + tid] = vd;
            off_src[goff + tid] = g * EPER + eso;
            off_dst[goff + tid] = g * EPER + edo;
            dis[goff + tid] = rsqrtf(1.0f + (float)vd);
        }
        __syncthreads();
        if (tid < NN) { ps[tid] = eso; pd[tid] = edo; }
        __syncthreads();
        for (int e = tid; e < EPER; e += 1024) {
            int s = es[e] - goff, d = ed[e] - goff;
            int p = atomicAdd(&ps[s], 1); sdl[p] = (u16)d;
            int q = atomicAdd(&pd[d], 1); ssl[q] = (u16)s;
        }
        __syncthreads();
        u32* wd = (u32*)(srt_dst + (size_t)g * EPER);
        u32* ws = (u32*)(srt_src + (size_t)g * EPER);
        const u32* rd = (const u32*)sdl;
        const u32* rs = (const u32*)ssl;
        for (int i = tid; i < EPER / 2; i += 1024) { wd[i] = rd[i]; ws[i] = rs[i]; }
        return;
    }
    // -------- xw role: 512 rows per block --------
    int nbase = (b - TB) * 512;
    for (int i = tid; i < INC * HH; i += 1024) {
        int k = i >> 5, n = i & 31;
        sW[n * XTS + k] = (u16)bfr(W[i]);
    }
    for (int i = tid; i < 512 * 32; i += 1024) {
        int r = i >> 5, q = i & 31;
        float4 v = ((const float4*)(x + (size_t)(nbase + r) * INC))[q];
        u32* dst = (u32*)&sX[r * XTS + q * 4];
        dst[0] = pk2(v.x, v.y);
        dst[1] = pk2(v.z, v.w);
    }
    __syncthreads();
    int wave = tid >> 6, lane = tid & 63;
    int lc = lane & 31, half = lane >> 5;
    f32x16 acc;
#pragma unroll
    for (int r = 0; r < 16; r++) acc[r] = 0.f;
#pragma unroll
    for (int kc = 0; kc < 8; kc++) {
        bf16x8 af  = *(const bf16x8*)&sX[(wave * 32 + lc) * XTS + kc * 16 + half * 8];
        bf16x8 bfv = *(const bf16x8*)&sW[lc * XTS + kc * 16 + half * 8];
        acc = __builtin_amdgcn_mfma_f32_32x32x16_bf16(af, bfv, acc, 0, 0, 0);
    }
#pragma unroll
    for (int r = 0; r < 16; r++) {
        int m = (r & 3) + 8 * (r >> 2) + 4 * half;
        int rowg = nbase + wave * 32 + m;
        xwb[(size_t)rowg * HH + lc] = (u16)bfr(acc[r]);
    }
}

// -------- GCN gather (bf16 xw, u16 indices, XCD-swizzled blocks): hb bf16 only
__global__ __launch_bounds__(256) void k_gcng(const u16* __restrict__ ssrc, const int* __restrict__ od,
                                              const int* __restrict__ cd, const u32* __restrict__ xwb32,
                                              const float* __restrict__ dis, const float* __restrict__ bias,
                                              u32* __restrict__ hb32) {
    int tid = threadIdx.x;
    int b = blockIdx.x;
    int r8 = b & 7, j = b >> 3;
    int g = r8 + 8 * (j & 15);
    int chunk = j >> 4;
    int n = g * NN + chunk * 16 + (tid >> 4), cp = tid & 15;
    int goff = g * NN;
    int base = od[n], cnt = cd[n];
    float dn = dis[n];
    u32 us = xwb32[(size_t)n * 16 + cp];
    float a0 = dn * blo(us), a1 = dn * bhi(us);
    int i = 0;
    for (; i + 4 <= cnt; i += 4) {
        int s0 = goff + ssrc[base + i],     s1v = goff + ssrc[base + i + 1];
        int s2 = goff + ssrc[base + i + 2], s3  = goff + ssrc[base + i + 3];
        float d0 = dis[s0], d1 = dis[s1v], d2 = dis[s2], d3 = dis[s3];
        u32 u0 = xwb32[(size_t)s0 * 16 + cp];
        u32 u1 = xwb32[(size_t)s1v * 16 + cp];
        u32 u2 = xwb32[(size_t)s2 * 16 + cp];
        u32 u3 = xwb32[(size_t)s3 * 16 + cp];
        a0 += d0 * blo(u0) + d1 * blo(u1) + d2 * blo(u2) + d3 * blo(u3);
        a1 += d0 * bhi(u0) + d1 * bhi(u1) + d2 * bhi(u2) + d3 * bhi(u3);
    }
    for (; i < cnt; i++) {
        int s0 = goff + ssrc[base + i]; float d0 = dis[s0];
        u32 u0 = xwb32[(size_t)s0 * 16 + cp];
        a0 += d0 * blo(u0); a1 += d0 * bhi(u0);
    }
    float v0 = fmaxf(dn * a0 + bias[2 * cp], 0.f);
    float v1 = fmaxf(dn * a1 + bias[2 * cp + 1], 0.f);
    hb32[(size_t)n * 16 + cp] = pk2(v0, v1);
}

// ------- s1 via MFMA: logits = hb @ pool1_W + b, softmax in-register
__global__ __launch_bounds__(256) void k_s1m(const u32* __restrict__ hb32, const float* __restrict__ W,
                                             const float* __restrict__ bias, const int* __restrict__ csrc,
                                             u16* __restrict__ s1b, float* __restrict__ den1) {
    __shared__ u16 sH[128 * ZTS];
    __shared__ u16 sW[128 * ZTS];
    int tid = threadIdx.x;
    int nbase = blockIdx.x * 128;
    for (int i = tid; i < HH * KP1; i += 256) {
        int k = i / KP1, n = i - k * KP1;
        sW[n * ZTS + k] = (u16)bfr(W[i]);
    }
    for (int i = tid; i < 28 * 16; i += 256) {
        int n = 100 + (i >> 4), q = i & 15;
        ((u32*)sW)[n * (ZTS / 2) + q] = 0;
    }
    for (int i = tid; i < 128 * 16; i += 256) {
        int r = i >> 4, q = i & 15;
        ((u32*)sH)[r * (ZTS / 2) + q] = hb32[(size_t)(nbase + r) * 16 + q];
    }
    __syncthreads();
    int wave = tid >> 6, lane = tid & 63;
    int lc = lane & 31, half = lane >> 5;
    f32x16 acc[4];
#pragma unroll
    for (int t = 0; t < 4; t++)
#pragma unroll
        for (int r = 0; r < 16; r++) acc[t][r] = 0.f;
#pragma unroll
    for (int kc = 0; kc < 2; kc++) {
        bf16x8 af = *(const bf16x8*)&sH[(wave * 32 + lc) * ZTS + kc * 16 + half * 8];
#pragma unroll
        for (int t = 0; t < 4; t++) {
            bf16x8 bfv = *(const bf16x8*)&sW[(t * 32 + lc) * ZTS + kc * 16 + half * 8];
            acc[t] = __builtin_amdgcn_mfma_f32_32x32x16_bf16(af, bfv, acc[t], 0, 0, 0);
        }
    }
    float s[16], q[16];
#pragma unroll
    for (int r = 0; r < 16; r++) { s[r] = 0.f; q[r] = 0.f; }
#pragma unroll
    for (int t = 0; t < 4; t++) {
        int ch = t * 32 + lc;
        bool valid = ch < KP1;
        float bv = valid ? bias[ch] : 0.f;
#pragma unroll
        for (int r = 0; r < 16; r++) {
            float ev = valid ? __expf(acc[t][r] + bv) : 0.f;
            acc[t][r] = ev; s[r] += ev; q[r] = fmaf(ev, ev, q[r]);
        }
    }
#pragma unroll
    for (int off = 16; off >= 1; off >>= 1) {
#pragma unroll
        for (int r = 0; r < 16; r++) { s[r] += __shfl_xor(s[r], off); q[r] += __shfl_xor(q[r], off); }
    }
    float inv[16];
#pragma unroll
    for (int r = 0; r < 16; r++) inv[r] = 1.f / s[r];
#pragma unroll
    for (int t = 0; t < 4; t++) {
        int ch = t * 32 + lc;
        if (ch < KP1) {
#pragma unroll
            for (int r = 0; r < 16; r++) {
                int lr = (r & 3) + 8 * (r >> 2) + 4 * half;
                int rowg = nbase + wave * 32 + lr;
                s1b[(size_t)rowg * KP1 + ch] = (u16)bfr(acc[t][r] * inv[r]);
            }
        }
    }
    float contrib = 0.f;
    if (lc == 0) {
#pragma unroll
        for (int r = 0; r < 16; r++) {
            int lr = (r & 3) + 8 * (r >> 2) + 4 * half;
            int rowg = nbase + wave * 32 + lr;
            contrib += (float)csrc[rowg] * q[r] * inv[r] * inv[r];
        }
    }
    contrib += __shfl_xor(contrib, 32);
    if (lane == 0) atomicAdd(&den1[nbase >> 9], contrib);
}

// ------------- t1 gather (bf16, u16 indices, XCD-swizzled): wave per node
__global__ __launch_bounds__(256) void k_t1g(const u16* __restrict__ sdst, const int* __restrict__ osr,
                                             const int* __restrict__ csr, const u32* __restrict__ s1b32,
                                             u32* __restrict__ t1b32) {
    int tid = threadIdx.x;
    int b = blockIdx.x;
    int r8 = b & 7, j = b >> 3;
    int g = r8 + 8 * (j & 15);
    int chunk = j >> 4;
    int n = g * NN + chunk * 4 + (tid >> 6), lane = tid & 63;
    if (lane >= 50) return;
    int goff = g * NN;
    int base = osr[n], cnt = csr[n];
    float a0 = 0.f, a1 = 0.f;
    int i = 0;
    for (; i + 4 <= cnt; i += 4) {
        int d0 = goff + sdst[base + i],     d1 = goff + sdst[base + i + 1];
        int d2 = goff + sdst[base + i + 2], d3 = goff + sdst[base + i + 3];
        u32 u0 = s1b32[(size_t)d0 * 50 + lane];
        u32 u1 = s1b32[(size_t)d1 * 50 + lane];
        u32 u2 = s1b32[(size_t)d2 * 50 + lane];
        u32 u3 = s1b32[(size_t)d3 * 50 + lane];
        a0 += (blo(u0) + blo(u1)) + (blo(u2) + blo(u3));
        a1 += (bhi(u0) + bhi(u1)) + (bhi(u2) + bhi(u3));
    }
    for (; i < cnt; i++) {
        int d0 = goff + sdst[base + i];
        u32 u0 = s1b32[(size_t)d0 * 50 + lane];
        a0 += blo(u0); a1 += bhi(u0);
    }
    t1b32[(size_t)n * 50 + lane] = pk2(a0, a1);
}

// ---- chpair staging helpers (bank/coalesce-clean, R6-verified).
__device__ __forceinline__ void ld_cp(const u32* __restrict__ sp, int rstr,
                                      u32& w0, u32& w1, u32& w2, u32& w3) {
    w0 = sp[0]; w1 = sp[rstr]; w2 = sp[2 * rstr]; w3 = sp[3 * rstr];
}
__device__ __forceinline__ void st_cp(u16* __restrict__ zb, int doff,
                                      u32 w0, u32 w1, u32 w2, u32 w3) {
    u32 lo01 = (w0 & 0xffffu) | (w1 << 16);
    u32 lo23 = (w2 & 0xffffu) | (w3 << 16);
    u32 hi01 = (w0 >> 16) | (w1 & 0xffff0000u);
    u32 hi23 = (w2 >> 16) | (w3 & 0xffff0000u);
    *(uint2*)&zb[doff]       = make_uint2(lo01, lo23);
    *(uint2*)&zb[doff + ZTS] = make_uint2(hi01, hi23);
}

#define GRAM_MFMA(zb)                                                                               \
    {                                                                                               \
        bf16x8 af0 = *(const bf16x8*)&(zb)[(132 + (2*mtb    )*32 + lc)*ZTS + mfh*16 + half*8];      \
        bf16x8 af1 = *(const bf16x8*)&(zb)[(132 + (2*mtb + 1)*32 + lc)*ZTS + mfh*16 + half*8];      \
        bf16x8 bv0 = *(const bf16x8*)&(zb)[((2*ctb    )*32 + lc)*ZTS + mfh*16 + half*8];            \
        bf16x8 bv1 = *(const bf16x8*)&(zb)[((2*ctb + 1)*32 + lc)*ZTS + mfh*16 + half*8];            \
        acc00 = __builtin_amdgcn_mfma_f32_32x32x16_bf16(af0, bv0, acc00, 0, 0, 0);                  \
        acc01 = __builtin_amdgcn_mfma_f32_32x32x16_bf16(af0, bv1, acc01, 0, 0, 0);                  \
        acc10 = __builtin_amdgcn_mfma_f32_32x32x16_bf16(af1, bv0, acc10, 0, 0, 0);                  \
        acc11 = __builtin_amdgcn_mfma_f32_32x32x16_bf16(af1, bv1, acc11, 0, 0, 0);                  \
    }

#define DUMP_TILE(AV, MT, CT, ADD)                                                                  \
    {                                                                                               \
        int l = (CT) * 32 + lc;                                                                     \
        if (l < 232) {                                                                              \
            _Pragma("unroll")                                                                       \
            for (int r = 0; r < 16; r++) {                                                          \
                int k = (MT) * 32 + (r & 3) + 8 * (r >> 2) + 4 * half;                              \
                if (k < KP1) {                                                                      \
                    if (ADD) sC[k * 232 + l] += AV[r];                                              \
                    else     sC[k * 232 + l] = AV[r];                                               \
                }                                                                                   \
            }                                                                                       \
        }                                                                                           \
    }

// === k_gramA: split-K gram partials, FULL-CHIP grid (256 blocks).
// Block b: graph g = b&127, K-half kh = b>>7 (8 chunks of 32 nodes). kh=b>>7 keeps
// both halves of a graph on the same XCD (128 % 8 == 0) for shared-row L2 hits.
__global__ __launch_bounds__(1024, 1) void k_gramA(const u32* __restrict__ s1b32, const u32* __restrict__ t1b32,
                                                   const u32* __restrict__ hb32, float* __restrict__ Cp) {
    __shared__ __align__(16) u16 sZ[2][ZTR * ZTS];   // 42.2 KB
    __shared__ float sC[CSZ];                // 92.8 KB partial gram tile
    int b = blockIdx.x;
    int g = b & (TB - 1), kh = b >> 7;
    int nbase = g * NN + kh * 256;
    int tid = threadIdx.x;
    int wave = tid >> 6, lane = tid & 63;
    int mfh = wave & 1;
    int mtb = (wave >> 1) & 1;
    int ctb = wave >> 2;
    int lc = lane & 31, half = lane >> 5;

    f32x16 acc00, acc01, acc10, acc11;
#pragma unroll
    for (int r = 0; r < 16; r++) { acc00[r] = 0.f; acc01[r] = 0.f; acc10[r] = 0.f; acc11[r] = 0.f; }

    // staging role (thread-invariant): chpair cp, node-quad rq
    int cp = (tid & 7) + ((tid >> 6) << 3);
    int rq = (tid >> 3) & 7;
    bool act = cp < 116;
    const u32* sp;
    int rstr;
    if (cp < 50)      { sp = t1b32 + cp;        rstr = 50; }
    else if (cp < 66) { sp = hb32 + (cp - 50);  rstr = 16; }
    else              { sp = s1b32 + (cp - 66); rstr = 50; }
    sp += (size_t)(nbase + rq * 4) * rstr;
    int step = rstr * 32;
    int doff = (2 * cp) * ZTS + rq * 4;

    for (int i = tid; i < 32 * ZTS; i += 1024) {
        int r = 232 + i / ZTS, c = i % ZTS;
        sZ[0][r * ZTS + c] = 0; sZ[1][r * ZTS + c] = 0;
    }
    u32 a0, a1, a2, a3, b0 = 0, b1 = 0, b2 = 0, b3 = 0;
    if (act) {
        ld_cp(sp, rstr, a0, a1, a2, a3);
        st_cp(sZ[0], doff, a0, a1, a2, a3);
        sp += step;
        ld_cp(sp, rstr, b0, b1, b2, b3);
        sp += step;
    }
    __syncthreads();

    for (int nt = 0; nt < 8; nt += 2) {
        GRAM_MFMA(sZ[0]);
        if (act) {
            st_cp(sZ[1], doff, b0, b1, b2, b3);
            if (nt + 2 < 8) { ld_cp(sp, rstr, a0, a1, a2, a3); sp += step; }
        }
        __syncthreads();
        GRAM_MFMA(sZ[1]);
        if (act && nt + 2 < 8) {
            st_cp(sZ[0], doff, a0, a1, a2, a3);
            if (nt + 3 < 8) { ld_cp(sp, rstr, b0, b1, b2, b3); sp += step; }
        }
        __syncthreads();
    }
    // two-phase dump into sC (merge mfh halves)
    if (mfh == 0) {
        DUMP_TILE(acc00, 2 * mtb,     2 * ctb,     0)
        DUMP_TILE(acc01, 2 * mtb,     2 * ctb + 1, 0)
        DUMP_TILE(acc10, 2 * mtb + 1, 2 * ctb,     0)
        DUMP_TILE(acc11, 2 * mtb + 1, 2 * ctb + 1, 0)
    }
    __syncthreads();
    if (mfh == 1) {
        DUMP_TILE(acc00, 2 * mtb,     2 * ctb,     1)
        DUMP_TILE(acc01, 2 * mtb,     2 * ctb + 1, 1)
        DUMP_TILE(acc10, 2 * mtb + 1, 2 * ctb,     1)
        DUMP_TILE(acc11, 2 * mtb + 1, 2 * ctb + 1, 1)
    }
    __syncthreads();
    // coalesced partial store
    float4* dst = (float4*)(Cp + (size_t)b * CSZ);
    const float4* src = (const float4*)sC;
    for (int i = tid; i < CSZ / 4; i += 1024) dst[i] = src[i];
}

// === k_fin2: sum 2 partials -> finalize (losses, sd, normalize) -> s2 -> head.
__global__ __launch_bounds__(1024, 1) void k_fin2(const float* __restrict__ Cp, const float* __restrict__ aux,
                                                  const float* __restrict__ relW, const float* __restrict__ relB,
                                                  const float* __restrict__ rootW,
                                                  const float* __restrict__ p2W, const float* __restrict__ p2B,
                                                  const float* __restrict__ relW3, const float* __restrict__ relb3,
                                                  const float* __restrict__ rootW3,
                                                  const float* __restrict__ l1W, const float* __restrict__ l1b,
                                                  const float* __restrict__ l2W, const float* __restrict__ l2b,
                                                  float* __restrict__ out) {
    __shared__ float sC[CSZ];                // 92.8 KB: summed gram -> normalized A + P1
    __shared__ float ov[10560];              // 42.2 KB s2 overlay
    __shared__ float sRow[KP1], sd[KP1];
    __shared__ float sScal[3];
    __shared__ float sL1;
    int g = blockIdx.x;
    int tid = threadIdx.x;

    float* sXo = ov;                         // 3200  (x1p then x2)
    float* sYo = ov + 3200;                  // 3200  (y = A @ x1p)
    float* sS2 = ov + 6400;                  // 1000
    float* sT2 = ov + 7400;                  // 1000
    float* sA2 = ov + 8400;                  // 100
    float* sB2 = ov + 8500;                  // 100
    float* red = ov + 8600;                  // 100
    float* sP2 = ov + 8700;                  // 320
    float* sY3 = ov + 9020;                  // 320
    float* sAn = ov + 9340;                  // 100
    float* sG  = ov + 9440;                  // 32
    float* sG1 = ov + 9472;                  // 32
    float* sL  = ov + 9504;                  // 10
    float* sdd = ov + 9514;                  // 10
    float* sLse = ov + 9524;                 // 1

    if (tid < KP1) sRow[tid] = 0.f;
    if (tid < 3) sScal[tid] = 0.f;
    if (tid < 32) sG[tid] = 0.f;
    // sum the two K-half partials (kh0 at g, kh1 at g+128)
    {
        const float4* pa = (const float4*)(Cp + (size_t)g * CSZ);
        const float4* pb = (const float4*)(Cp + (size_t)(g + TB) * CSZ);
        float4* dst = (float4*)sC;
        for (int i = tid; i < CSZ / 4; i += 1024) {
            float4 a = pa[i], b = pb[i];
            a.x += b.x; a.y += b.y; a.z += b.z; a.w += b.w;
            dst[i] = a;
        }
    }
    __syncthreads();
    // ---- finalize sweep: row sums (minus diag), troa/trss/ssq
    {
        float ssq = 0.f, trss = 0.f, troa = 0.f;
        for (int idx = tid; idx < KP1 * 58; idx += 1024) {
            int k = idx / 58, q = idx - k * 58;
            float4 s = *(const float4*)&sC[k * 232 + q * 4];
            int c = q * 4;
            if (c < 100) {
                float rs = (s.x + s.y) + (s.z + s.w);
                if (k >= c && k < c + 4) { float d = ((const float*)&s)[k - c]; troa += d; rs -= d; }
                atomicAdd(&sRow[k], rs);
            } else if (c >= 132) {
                ssq += s.x * s.x + s.y * s.y + s.z * s.z + s.w * s.w;
                int l0 = c - 132;
                if (k >= l0 && k < l0 + 4) trss += ((const float*)&s)[k - l0];
            }
        }
#pragma unroll
        for (int off = 32; off >= 1; off >>= 1) {
            ssq  += __shfl_xor(ssq, off);
            trss += __shfl_xor(trss, off);
            troa += __shfl_xor(troa, off);
        }
        if ((tid & 63) == 0) {
            atomicAdd(&sScal[0], troa);
            atomicAdd(&sScal[1], trss);
            atomicAdd(&sScal[2], ssq);
        }
    }
    __syncthreads();
    if (tid == 0) {
        float o1 = sqrtf(fmaxf(2.f - 2.f * sScal[1] / (sqrtf(sScal[2]) * 10.f), 0.f));  // sqrt(K1)=10
        sL1 = -(sScal[0] / aux[g]) + o1;     // aux[g] = den1 (from k_s1m)
    }
    if (tid < KP1) sd[tid] = sqrtf(sRow[tid]) + 1e-15f;
    __syncthreads();
    // ---- normalize A IN PLACE (cols 0..99, stride 232); stage x1p -> sXo
    for (int i = tid; i < KP1 * KP1; i += 1024) {
        int k = i / KP1, l = i - k * KP1;
        float v = sC[k * 232 + l];
        sC[k * 232 + l] = (k == l) ? 0.f : v / (sd[k] * sd[l]);
    }
    for (int i = tid; i < KP1 * HH; i += 1024) {
        int k = i >> 5, c = i & 31;
        sXo[i] = sC[k * 232 + 100 + c];
    }
    __syncthreads();

    // ================= stage 2 (from LDS) =================
    int n = tid >> 2, cq = tid & 3;          // 400 active threads for y / x2
    if (tid < 400) {
        float yv[8];
#pragma unroll
        for (int j = 0; j < 8; j++) yv[j] = 0.f;
        for (int mq = 0; mq < 25; mq++) {
            float4 a4 = *(const float4*)&sC[n * 232 + mq * 4];
            const float* xb = &sXo[(mq * 4) * HH + cq * 8];
            float aa[4] = {a4.x, a4.y, a4.z, a4.w};
#pragma unroll
            for (int mm = 0; mm < 4; mm++) {
                const float* xr = xb + mm * HH;
#pragma unroll
                for (int j = 0; j < 8; j++) yv[j] = fmaf(aa[mm], xr[j], yv[j]);
            }
        }
#pragma unroll
        for (int j = 0; j < 8; j++) sYo[n * HH + cq * 8 + j] = yv[j];
    }
    __syncthreads();
    float x2v[8];
    if (tid < 400) {
#pragma unroll
        for (int j = 0; j < 8; j++) x2v[j] = relB[cq * 8 + j];
        for (int j = 0; j < 32; j++) {
            float yj = sYo[n * HH + j];
            float xj = sXo[n * HH + j];
            float4 r0 = *(const float4*)&relW[j * 32 + cq * 8];
            float4 r1v = *(const float4*)&relW[j * 32 + cq * 8 + 4];
            float4 q0 = *(const float4*)&rootW[j * 32 + cq * 8];
            float4 q1 = *(const float4*)&rootW[j * 32 + cq * 8 + 4];
            x2v[0] += yj * r0.x + xj * q0.x;  x2v[1] += yj * r0.y + xj * q0.y;
            x2v[2] += yj * r0.z + xj * q0.z;  x2v[3] += yj * r0.w + xj * q0.w;
            x2v[4] += yj * r1v.x + xj * q1.x; x2v[5] += yj * r1v.y + xj * q1.y;
            x2v[6] += yj * r1v.z + xj * q1.z; x2v[7] += yj * r1v.w + xj * q1.w;
        }
    }
    __syncthreads();
    if (tid < 400) {
#pragma unroll
        for (int j = 0; j < 8; j++) sXo[n * HH + cq * 8 + j] = fmaxf(x2v[j], 0.f);
    }
    __syncthreads();
    // s2 = softmax(x2 @ p2W + p2B); d2 and den2 partials
    if (tid < KP1) {
        float lg[10];
#pragma unroll
        for (int j = 0; j < 10; j++) lg[j] = p2B[j];
        for (int c = 0; c < 32; c++) {
            float xv = sXo[tid * HH + c];
#pragma unroll
            for (int j = 0; j < 10; j++) lg[j] = fmaf(xv, p2W[c * 10 + j], lg[j]);
        }
        float mx = lg[0];
#pragma unroll
        for (int j = 1; j < 10; j++) mx = fmaxf(mx, lg[j]);
        float se = 0.f;
#pragma unroll
        for (int j = 0; j < 10; j++) { lg[j] = __expf(lg[j] - mx); se += lg[j]; }
        float inv = 1.f / se, sq = 0.f;
#pragma unroll
        for (int j = 0; j < 10; j++) { float sv = lg[j] * inv; sS2[tid * 10 + j] = sv; sq += sv * sv; }
        float d2 = 0.f;
        for (int mq = 0; mq < 25; mq++) {
            float4 a4 = *(const float4*)&sC[tid * 232 + mq * 4];
            d2 += a4.x + a4.y + a4.z + a4.w;
        }
        red[tid] = d2 * sq;
    }
    __syncthreads();
    // t2 = A @ s2 ; P2 = s2^T x2
    for (int p = tid; p < KP1 * KP2; p += 1024) {
        int n2 = p / 10, jj = p % 10;
        float a = 0.f;
        for (int m = 0; m < KP1; m++) a = fmaf(sC[n2 * 232 + m], sS2[m * 10 + jj], a);
        sT2[p] = a;
    }
    if (tid < KP2 * HH) {
        int k = tid >> 5, cc = tid & 31;
        float a = 0.f;
        for (int n2 = 0; n2 < KP1; n2++) a = fmaf(sS2[n2 * 10 + k], sXo[n2 * HH + cc], a);
        sP2[tid] = a;
    }
    __syncthreads();
    if (tid < 100) {
        int k = tid / 10, l = tid % 10;
        float oa = 0.f, ss = 0.f;
        for (int n2 = 0; n2 < KP1; n2++) {
            float sk = sS2[n2 * 10 + k];
            oa = fmaf(sk, sT2[n2 * 10 + l], oa);
            ss = fmaf(sk, sS2[n2 * 10 + l], ss);
        }
        sA2[tid] = oa; sB2[tid] = ss;
    }
    __syncthreads();
    if (tid == 0) {
        float den2 = 0.f;
        for (int i = 0; i < 100; i++) den2 += red[i];
        float troa = 0.f, trss = 0.f, ssq = 0.f;
        for (int k = 0; k < 10; k++) { troa += sA2[k * 10 + k]; trss += sB2[k * 10 + k]; }
        for (int i = 0; i < 100; i++) ssq += sB2[i] * sB2[i];
        float o2 = sqrtf(fmaxf(2.f - 2.f * trss / (sqrtf(ssq) * 3.16227766f), 0.f)); // sqrt(10)
        float l2 = -(troa / den2) + o2;
        atomicAdd(&out[1280], (sL1 + l2) * (1.f / 128.f));   // fused k_loss
    }
    if (tid < 10) {
        float rs = 0.f;
        for (int l = 0; l < 10; l++) if (l != tid) rs += sA2[tid * 10 + l];
        sdd[tid] = sqrtf(rs) + 1e-15f;
    }
    __syncthreads();
    if (tid < 100) {
        int k = tid / 10, l = tid % 10;
        sAn[tid] = (k == l) ? 0.f : sA2[tid] / (sdd[k] * sdd[l]);
    }
    __syncthreads();
    // ---- conv3 + mean + MLP head + log_softmax
    if (tid < KP2 * HH) {
        int k = tid >> 5, cc = tid & 31;
        float a = 0.f;
#pragma unroll
        for (int m = 0; m < 10; m++) a = fmaf(sAn[k * 10 + m], sP2[m * HH + cc], a);
        sY3[tid] = a;
    }
    __syncthreads();
    if (tid < KP2 * HH) {
        int k = tid >> 5, cc = tid & 31;
        float v = relb3[cc];
        for (int j = 0; j < 32; j++)
            v += sY3[k * HH + j] * relW3[j * 32 + cc] + sP2[k * HH + j] * rootW3[j * 32 + cc];
        atomicAdd(&sG[cc], v * 0.1f);        // mean over 10 nodes
    }
    __syncthreads();
    if (tid < 32) {
        float v = l1b[tid];
        for (int j = 0; j < 32; j++) v = fmaf(sG[j], l1W[j * 32 + tid], v);
        sG1[tid] = fmaxf(v, 0.f);
    }
    __syncthreads();
    if (tid < 10) {
        float v = l2b[tid];
        for (int j = 0; j < 32; j++) v = fmaf(sG1[j], l2W[j * 10 + tid], v);
        sL[tid] = v;
    }
    __syncthreads();
    if (tid == 0) {
        float mx = sL[0];
        for (int j = 1; j < 10; j++) mx = fmaxf(mx, sL[j]);
        float se = 0.f;
        for (int j = 0; j < 10; j++) se += expf(sL[j] - mx);
        *sLse = mx + logf(se);
    }
    __syncthreads();
    if (tid < 10) out[(size_t)g * 10 + tid] = sL[tid] - *sLse;
}

extern "C" void kernel_launch(void* const* d_in, const int* in_sizes, int n_in,
                              void* d_out, int out_size, void* d_ws, size_t ws_size,
                              hipStream_t stream) {
    const float* x    = (const float*)d_in[0];
    const int*   ei   = (const int*)d_in[1];
    const float* c1W  = (const float*)d_in[3];
    const float* c1b  = (const float*)d_in[4];
    const float* p1W  = (const float*)d_in[5];
    const float* p1b  = (const float*)d_in[6];
    const float* relW2  = (const float*)d_in[7];
    const float* relb2  = (const float*)d_in[8];
    const float* rootW2 = (const float*)d_in[9];
    const float* p2W  = (const float*)d_in[10];
    const float* p2b  = (const float*)d_in[11];
    const float* relW3  = (const float*)d_in[12];
    const float* relb3  = (const float*)d_in[13];
    const float* rootW3 = (const float*)d_in[14];
    const float* l1W  = (const float*)d_in[15];
    const float* l1b  = (const float*)d_in[16];
    const float* l2W  = (const float*)d_in[17];
    const float* l2b  = (const float*)d_in[18];
    float* out = (float*)d_out;

    // ---- workspace layout
    int*  cnt_src = (int*)d_ws;                       // NT
    int*  cnt_dst = cnt_src + NT;                     // NT
    int*  off_src = cnt_dst + NT;                     // NT
    int*  off_dst = off_src + NT;                     // NT
    u16*  srt_dst = (u16*)(off_dst + NT);             // ET u16 (src-sorted, stores local dst)
    u16*  srt_src = srt_dst + ET;                     // ET u16 (dst-sorted, stores local src)
    float* dis = (float*)(srt_src + ET);              // NT
    u32*  xwb  = (u32*)(dis + NT);                    // NT*16 (bf16 x2)
    u32*  hb   = xwb + (size_t)NT * 16;               // NT*16
    u32*  s1b  = hb + (size_t)NT * 16;                // NT*50
    u32*  t1b  = s1b + (size_t)NT * 50;               // NT*50
    float* Cp   = (float*)(t1b + (size_t)NT * 50);    // 2*TB*CSZ (split-K partials)
    float* aux  = Cp + (size_t)2 * TB * CSZ;          // 128: den1

    k_pre<<<2 * TB, 1024, 0, stream>>>(ei, cnt_src, cnt_dst, off_src, off_dst,
                                       srt_dst, srt_src, dis, aux, x, c1W, (u16*)xwb, out);
    k_gcng<<<NT / 16, 256, 0, stream>>>(srt_src, off_dst, cnt_dst, xwb, dis, c1b, hb);
    k_s1m<<<NT / 128, 256, 0, stream>>>(hb, p1W, p1b, cnt_src, (u16*)s1b, aux /*den1*/);
    k_t1g<<<NT / 4, 256, 0, stream>>>(srt_dst, off_src, cnt_src, s1b, t1b);
    k_gramA<<<2 * TB, 1024, 0, stream>>>(s1b, t1b, hb, Cp);
    k_fin2<<<TB, 1024, 0, stream>>>(Cp, aux, relW2, relb2, rootW2, p2W, p2b,
                                    relW3, relb3, rootW3, l1W, l1b, l2W, l2b, out);
}

// Round 11
// 234.573 us; speedup vs baseline: 1.0817x; 1.0817x over previous
//
#include <hip/hip_runtime.h>
#include <hip/hip_bf16.h>

// Problem constants (match reference)
#define TB   128          // batch B
#define NN   512          // nodes per graph
#define INC  128          // IN_C
#define HH   32           // HID
#define KP1  100          // K1
#define KP2  10           // K2
#define OC   10           // OUT_C
#define EPER 8192         // edges per graph
#define NT   (TB*NN)      // 65536 total nodes
#define ET   (TB*EPER)    // 1048576 total edges
#define ZTR  264          // gram ZT rows: 232 Z-cols + 32 zero pad (partial MFMA tiles)
#define ZTS  40           // ZT row stride in u16 (80 B, 16B-aligned for ds_read_b128)
#define XTS  136          // xw row stride in u16 (272 B, 16B-aligned)

typedef unsigned int  u32;
typedef unsigned short u16;
typedef __attribute__((ext_vector_type(8))) short bf16x8;   // 8 bf16 = 4 VGPR (MFMA A/B frag)
typedef __attribute__((ext_vector_type(16))) float f32x16;  // MFMA C/D frag

// bf16 helpers (RNE encode; exact decode)
__device__ __forceinline__ u32 bfr(float f) {
    u32 b = __float_as_uint(f);
    return (b + 0x7fffu + ((b >> 16) & 1u)) >> 16;
}
__device__ __forceinline__ u32 pk2(float a, float b) { return bfr(a) | (bfr(b) << 16); }
__device__ __forceinline__ float blo(u32 u) { return __uint_as_float(u << 16); }
__device__ __forceinline__ float bhi(u32 u) { return __uint_as_float(u & 0xffff0000u); }

// ==== k_pre: sort (blocks 0..127) ∥ xw (blocks 128..255), one launch ====
__global__ __launch_bounds__(1024) void k_pre(const int* __restrict__ ei,
                                              int* __restrict__ cnt_src, int* __restrict__ cnt_dst,
                                              int* __restrict__ off_src, int* __restrict__ off_dst,
                                              u16* __restrict__ srt_dst, u16* __restrict__ srt_src,
                                              float* __restrict__ dis, float* __restrict__ aux,
                                              const float* __restrict__ x, const float* __restrict__ W,
                                              u16* __restrict__ xwb, float* __restrict__ out) {
    __shared__ __align__(16) u16 sX[512 * XTS];   // 139.3 KB (xw staging; sort overlays first 40 KB)
    __shared__ __align__(16) u16 sW[32 * XTS];    // 8.7 KB
    int tid = threadIdx.x, b = blockIdx.x;
    if (b < TB) {
        // -------- sort role --------
        int* hs = (int*)sX;
        int* hd = hs + NN;
        int* ps = hd + NN;
        int* pd = ps + NN;
        u16* sdl = (u16*)(pd + NN);
        u16* ssl = sdl + EPER;
        int g = b, goff = g * NN;
        if (tid == 0) aux[g] = 0.f;               // den1 accumulator zero
        if (g == 0 && tid == 0) out[1280] = 0.f;  // loss accumulator zero
        if (tid < NN) { hs[tid] = 0; hd[tid] = 0; }
        __syncthreads();
        const int* es = ei + (size_t)g * EPER;
        const int* ed = ei + ET + (size_t)g * EPER;
        for (int e = tid; e < EPER; e += 1024) {
            atomicAdd(&hs[es[e] - goff], 1);
            atomicAdd(&hd[ed[e] - goff], 1);
        }
        __syncthreads();
        int vs = 0, vd = 0;
        if (tid < NN) { vs = hs[tid]; vd = hd[tid]; ps[tid] = vs; pd[tid] = vd; }
        __syncthreads();
        for (int off = 1; off < NN; off <<= 1) {
            int xa = 0, xb = 0;
            if (tid < NN) {
                xa = ps[tid]; xb = pd[tid];
                if (tid >= off) { xa += ps[tid - off]; xb += pd[tid - off]; }
            }
            __syncthreads();
            if (tid < NN) { ps[tid] = xa; pd[tid] = xb; }
            __syncthreads();
        }
        int eso = 0, edo = 0;
        if (tid < NN) {
            eso = ps[tid] - vs; edo = pd[tid] - vd;
            cnt_src[goff + tid] = vs;  cnt_dst[goff + tid] = vd;
            off_src[goff + tid] = g * EPER + eso;
            off_dst[goff + tid] = g * EPER + edo;
            dis[goff + tid] = rsqrtf(1.0f + (float)vd);
        }
        __syncthreads();
        if (tid < NN) { ps[tid] = eso; pd[tid] = edo; }
        __syncthreads();
        for (int e = tid; e < EPER; e += 1024) {
            int s = es[e] - goff, d = ed[e] - goff;
            int p = atomicAdd(&ps[s], 1); sdl[p] = (u16)d;
            int q = atomicAdd(&pd[d], 1); ssl[q] = (u16)s;
        }
        __syncthreads();
        u32* wd = (u32*)(srt_dst + (size_t)g * EPER);
        u32* ws = (u32*)(srt_src + (size_t)g * EPER);
        const u32* rd = (const u32*)sdl;
        const u32* rs = (const u32*)ssl;
        for (int i = tid; i < EPER / 2; i += 1024) { wd[i] = rd[i]; ws[i] = rs[i]; }
        return;
    }
    // -------- xw role: 512 rows per block --------
    int nbase = (b - TB) * 512;
    for (int i = tid; i < INC * HH; i += 1024) {
        int k = i >> 5, n = i & 31;
        sW[n * XTS + k] = (u16)bfr(W[i]);
    }
    for (int i = tid; i < 512 * 32; i += 1024) {
        int r = i >> 5, q = i & 31;
        float4 v = ((const float4*)(x + (size_t)(nbase + r) * INC))[q];
        u32* dst = (u32*)&sX[r * XTS + q * 4];
        dst[0] = pk2(v.x, v.y);
        dst[1] = pk2(v.z, v.w);
    }
    __syncthreads();
    int wave = tid >> 6, lane = tid & 63;
    int lc = lane & 31, half = lane >> 5;
    f32x16 acc;
#pragma unroll
    for (int r = 0; r < 16; r++) acc[r] = 0.f;
#pragma unroll
    for (int kc = 0; kc < 8; kc++) {
        bf16x8 af  = *(const bf16x8*)&sX[(wave * 32 + lc) * XTS + kc * 16 + half * 8];
        bf16x8 bfv = *(const bf16x8*)&sW[lc * XTS + kc * 16 + half * 8];
        acc = __builtin_amdgcn_mfma_f32_32x32x16_bf16(af, bfv, acc, 0, 0, 0);
    }
#pragma unroll
    for (int r = 0; r < 16; r++) {
        int m = (r & 3) + 8 * (r >> 2) + 4 * half;
        int rowg = nbase + wave * 32 + m;
        xwb[(size_t)rowg * HH + lc] = (u16)bfr(acc[r]);
    }
}

// -------- GCN gather (bf16 xw, u16 indices, XCD-swizzled blocks): hb bf16 only
__global__ __launch_bounds__(256) void k_gcng(const u16* __restrict__ ssrc, const int* __restrict__ od,
                                              const int* __restrict__ cd, const u32* __restrict__ xwb32,
                                              const float* __restrict__ dis, const float* __restrict__ bias,
                                              u32* __restrict__ hb32) {
    int tid = threadIdx.x;
    int b = blockIdx.x;
    int r8 = b & 7, j = b >> 3;
    int g = r8 + 8 * (j & 15);
    int chunk = j >> 4;
    int n = g * NN + chunk * 16 + (tid >> 4), cp = tid & 15;
    int goff = g * NN;
    int base = od[n], cnt = cd[n];
    float dn = dis[n];
    u32 us = xwb32[(size_t)n * 16 + cp];
    float a0 = dn * blo(us), a1 = dn * bhi(us);
    int i = 0;
    for (; i + 4 <= cnt; i += 4) {
        int s0 = goff + ssrc[base + i],     s1v = goff + ssrc[base + i + 1];
        int s2 = goff + ssrc[base + i + 2], s3  = goff + ssrc[base + i + 3];
        float d0 = dis[s0], d1 = dis[s1v], d2 = dis[s2], d3 = dis[s3];
        u32 u0 = xwb32[(size_t)s0 * 16 + cp];
        u32 u1 = xwb32[(size_t)s1v * 16 + cp];
        u32 u2 = xwb32[(size_t)s2 * 16 + cp];
        u32 u3 = xwb32[(size_t)s3 * 16 + cp];
        a0 += d0 * blo(u0) + d1 * blo(u1) + d2 * blo(u2) + d3 * blo(u3);
        a1 += d0 * bhi(u0) + d1 * bhi(u1) + d2 * bhi(u2) + d3 * bhi(u3);
    }
    for (; i < cnt; i++) {
        int s0 = goff + ssrc[base + i]; float d0 = dis[s0];
        u32 u0 = xwb32[(size_t)s0 * 16 + cp];
        a0 += d0 * blo(u0); a1 += d0 * bhi(u0);
    }
    float v0 = fmaxf(dn * a0 + bias[2 * cp], 0.f);
    float v1 = fmaxf(dn * a1 + bias[2 * cp + 1], 0.f);
    hb32[(size_t)n * 16 + cp] = pk2(v0, v1);
}

// ------- s1 via MFMA: logits = hb @ pool1_W + b, softmax in-register
__global__ __launch_bounds__(256) void k_s1m(const u32* __restrict__ hb32, const float* __restrict__ W,
                                             const float* __restrict__ bias, const int* __restrict__ csrc,
                                             u16* __restrict__ s1b, float* __restrict__ den1) {
    __shared__ u16 sH[128 * ZTS];
    __shared__ u16 sW[128 * ZTS];
    int tid = threadIdx.x;
    int nbase = blockIdx.x * 128;
    for (int i = tid; i < HH * KP1; i += 256) {
        int k = i / KP1, n = i - k * KP1;
        sW[n * ZTS + k] = (u16)bfr(W[i]);
    }
    for (int i = tid; i < 28 * 16; i += 256) {
        int n = 100 + (i >> 4), q = i & 15;
        ((u32*)sW)[n * (ZTS / 2) + q] = 0;
    }
    for (int i = tid; i < 128 * 16; i += 256) {
        int r = i >> 4, q = i & 15;
        ((u32*)sH)[r * (ZTS / 2) + q] = hb32[(size_t)(nbase + r) * 16 + q];
    }
    __syncthreads();
    int wave = tid >> 6, lane = tid & 63;
    int lc = lane & 31, half = lane >> 5;
    f32x16 acc[4];
#pragma unroll
    for (int t = 0; t < 4; t++)
#pragma unroll
        for (int r = 0; r < 16; r++) acc[t][r] = 0.f;
#pragma unroll
    for (int kc = 0; kc < 2; kc++) {
        bf16x8 af = *(const bf16x8*)&sH[(wave * 32 + lc) * ZTS + kc * 16 + half * 8];
#pragma unroll
        for (int t = 0; t < 4; t++) {
            bf16x8 bfv = *(const bf16x8*)&sW[(t * 32 + lc) * ZTS + kc * 16 + half * 8];
            acc[t] = __builtin_amdgcn_mfma_f32_32x32x16_bf16(af, bfv, acc[t], 0, 0, 0);
        }
    }
    float s[16], q[16];
#pragma unroll
    for (int r = 0; r < 16; r++) { s[r] = 0.f; q[r] = 0.f; }
#pragma unroll
    for (int t = 0; t < 4; t++) {
        int ch = t * 32 + lc;
        bool valid = ch < KP1;
        float bv = valid ? bias[ch] : 0.f;
#pragma unroll
        for (int r = 0; r < 16; r++) {
            float ev = valid ? __expf(acc[t][r] + bv) : 0.f;
            acc[t][r] = ev; s[r] += ev; q[r] = fmaf(ev, ev, q[r]);
        }
    }
#pragma unroll
    for (int off = 16; off >= 1; off >>= 1) {
#pragma unroll
        for (int r = 0; r < 16; r++) { s[r] += __shfl_xor(s[r], off); q[r] += __shfl_xor(q[r], off); }
    }
    float inv[16];
#pragma unroll
    for (int r = 0; r < 16; r++) inv[r] = 1.f / s[r];
#pragma unroll
    for (int t = 0; t < 4; t++) {
        int ch = t * 32 + lc;
        if (ch < KP1) {
#pragma unroll
            for (int r = 0; r < 16; r++) {
                int lr = (r & 3) + 8 * (r >> 2) + 4 * half;
                int rowg = nbase + wave * 32 + lr;
                s1b[(size_t)rowg * KP1 + ch] = (u16)bfr(acc[t][r] * inv[r]);
            }
        }
    }
    float contrib = 0.f;
    if (lc == 0) {
#pragma unroll
        for (int r = 0; r < 16; r++) {
            int lr = (r & 3) + 8 * (r >> 2) + 4 * half;
            int rowg = nbase + wave * 32 + lr;
            contrib += (float)csrc[rowg] * q[r] * inv[r] * inv[r];
        }
    }
    contrib += __shfl_xor(contrib, 32);
    if (lane == 0) atomicAdd(&den1[nbase >> 9], contrib);
}

// ------------- t1 gather (bf16, u16 indices, XCD-swizzled): wave per node
__global__ __launch_bounds__(256) void k_t1g(const u16* __restrict__ sdst, const int* __restrict__ osr,
                                             const int* __restrict__ csr, const u32* __restrict__ s1b32,
                                             u32* __restrict__ t1b32) {
    int tid = threadIdx.x;
    int b = blockIdx.x;
    int r8 = b & 7, j = b >> 3;
    int g = r8 + 8 * (j & 15);
    int chunk = j >> 4;
    int n = g * NN + chunk * 4 + (tid >> 6), lane = tid & 63;
    if (lane >= 50) return;
    int goff = g * NN;
    int base = osr[n], cnt = csr[n];
    float a0 = 0.f, a1 = 0.f;
    int i = 0;
    for (; i + 4 <= cnt; i += 4) {
        int d0 = goff + sdst[base + i],     d1 = goff + sdst[base + i + 1];
        int d2 = goff + sdst[base + i + 2], d3 = goff + sdst[base + i + 3];
        u32 u0 = s1b32[(size_t)d0 * 50 + lane];
        u32 u1 = s1b32[(size_t)d1 * 50 + lane];
        u32 u2 = s1b32[(size_t)d2 * 50 + lane];
        u32 u3 = s1b32[(size_t)d3 * 50 + lane];
        a0 += (blo(u0) + blo(u1)) + (blo(u2) + blo(u3));
        a1 += (bhi(u0) + bhi(u1)) + (bhi(u2) + bhi(u3));
    }
    for (; i < cnt; i++) {
        int d0 = goff + sdst[base + i];
        u32 u0 = s1b32[(size_t)d0 * 50 + lane];
        a0 += blo(u0); a1 += bhi(u0);
    }
    t1b32[(size_t)n * 50 + lane] = pk2(a0, a1);
}

// ---- chpair staging helpers (bank/coalesce-clean, R6-verified).
__device__ __forceinline__ void ld_cp(const u32* __restrict__ sp, int rstr,
                                      u32& w0, u32& w1, u32& w2, u32& w3) {
    w0 = sp[0]; w1 = sp[rstr]; w2 = sp[2 * rstr]; w3 = sp[3 * rstr];
}
__device__ __forceinline__ void st_cp(u16* __restrict__ zb, int doff,
                                      u32 w0, u32 w1, u32 w2, u32 w3) {
    u32 lo01 = (w0 & 0xffffu) | (w1 << 16);
    u32 lo23 = (w2 & 0xffffu) | (w3 << 16);
    u32 hi01 = (w0 >> 16) | (w1 & 0xffff0000u);
    u32 hi23 = (w2 >> 16) | (w3 & 0xffff0000u);
    *(uint2*)&zb[doff]       = make_uint2(lo01, lo23);
    *(uint2*)&zb[doff + ZTS] = make_uint2(hi01, hi23);
}

#define GRAM_MFMA(zb)                                                                               \
    {                                                                                               \
        bf16x8 af0 = *(const bf16x8*)&(zb)[(132 + (2*mtb    )*32 + lc)*ZTS + mfh*16 + half*8];      \
        bf16x8 af1 = *(const bf16x8*)&(zb)[(132 + (2*mtb + 1)*32 + lc)*ZTS + mfh*16 + half*8];      \
        bf16x8 bv0 = *(const bf16x8*)&(zb)[((2*ctb    )*32 + lc)*ZTS + mfh*16 + half*8];            \
        bf16x8 bv1 = *(const bf16x8*)&(zb)[((2*ctb + 1)*32 + lc)*ZTS + mfh*16 + half*8];            \
        acc00 = __builtin_amdgcn_mfma_f32_32x32x16_bf16(af0, bv0, acc00, 0, 0, 0);                  \
        acc01 = __builtin_amdgcn_mfma_f32_32x32x16_bf16(af0, bv1, acc01, 0, 0, 0);                  \
        acc10 = __builtin_amdgcn_mfma_f32_32x32x16_bf16(af1, bv0, acc10, 0, 0, 0);                  \
        acc11 = __builtin_amdgcn_mfma_f32_32x32x16_bf16(af1, bv1, acc11, 0, 0, 0);                  \
    }

#define DUMP_TILE(AV, MT, CT, ADD)                                                                  \
    {                                                                                               \
        int l = (CT) * 32 + lc;                                                                     \
        if (l < 232) {                                                                              \
            _Pragma("unroll")                                                                       \
            for (int r = 0; r < 16; r++) {                                                          \
                int k = (MT) * 32 + (r & 3) + 8 * (r >> 2) + 4 * half;                              \
                if (k < KP1) {                                                                      \
                    if (ADD) sC[k * 232 + l] += AV[r];                                              \
                    else     sC[k * 232 + l] = AV[r];                                               \
                }                                                                                   \
            }                                                                                       \
        }                                                                                           \
    }

// === k_gram2: gram + finalize + FULL stage-2 (conv2/pool2/conv3/head) + loss.
// One block (1024 thr) per graph. Normalized A kept IN PLACE in sC (stride 232),
// P1 in sC cols 100..131. Tail parallelized: y/x2 at 800 threads (4 cols each),
// relW/rootW staged to LDS by threads 800..1023 concurrently with y, oa2/ss2 at
// 500 threads (5 K-chunks + combine).
__global__ __launch_bounds__(1024, 1) void k_gram2(const u32* __restrict__ s1b32, const u32* __restrict__ t1b32,
                                                   const u32* __restrict__ hb32, const float* __restrict__ aux,
                                                   const float* __restrict__ relW, const float* __restrict__ relB,
                                                   const float* __restrict__ rootW,
                                                   const float* __restrict__ p2W, const float* __restrict__ p2B,
                                                   const float* __restrict__ relW3, const float* __restrict__ relb3,
                                                   const float* __restrict__ rootW3,
                                                   const float* __restrict__ l1W, const float* __restrict__ l1b,
                                                   const float* __restrict__ l2W, const float* __restrict__ l2b,
                                                   float* __restrict__ out) {
    __shared__ __align__(16) u16 sZ[2][ZTR * ZTS];   // 42.2 KB (staging; s2 overlays after K-loop)
    __shared__ float sC[KP1 * 232];          // 92.8 KB: gram tile -> normalized A + P1
    __shared__ float sRow[KP1], sd[KP1];
    __shared__ float sScal[3];               // troa, trss, ssq
    __shared__ float sL1;                    // stage-1 loss term
    int g = blockIdx.x;
    int nbase = g * NN;
    int tid = threadIdx.x;
    int wave = tid >> 6, lane = tid & 63;
    int mfh = wave & 1;
    int mtb = (wave >> 1) & 1;
    int ctb = wave >> 2;
    int lc = lane & 31, half = lane >> 5;

    // ---- s2 overlay inside sZ (dead after the K-loop); 10560 floats available ----
    float* ov  = (float*)sZ;
    float* sXo = ov;                         // 3200  (x1p then x2)
    float* sYo = ov + 3200;                  // 3200  (y; later oa/ss partials)
    float* sS2 = ov + 6400;                  // 1000  (relW stage during y/x2)
    float* sT2 = ov + 7400;                  // 1000  (rootW stage during y/x2)
    float* sA2 = ov + 8400;                  // 100
    float* sB2 = ov + 8500;                  // 100
    float* red = ov + 8600;                  // 100
    float* sP2 = ov + 8700;                  // 320
    float* sY3 = ov + 9020;                  // 320
    float* sAn = ov + 9340;                  // 100
    float* sG  = ov + 9440;                  // 32
    float* sG1 = ov + 9472;                  // 32
    float* sL  = ov + 9504;                  // 10
    float* sdd = ov + 9514;                  // 10
    float* sLse = ov + 9524;                 // 1
    float* swR = ov + 6400;                  // 1024 relW  (overlaps sS2/sT2; dead before they're written)
    float* swQ = ov + 7424;                  // 1024 rootW (ends 8448; sA2 written later)
    float* oaP = ov + 3200;                  // 500 oa partials (sYo dead after x2)
    float* ssP = ov + 3700;                  // 500 ss partials

    f32x16 acc00, acc01, acc10, acc11;
#pragma unroll
    for (int r = 0; r < 16; r++) { acc00[r] = 0.f; acc01[r] = 0.f; acc10[r] = 0.f; acc11[r] = 0.f; }

    // ---- staging role (thread-invariant): chpair cp, node-quad rq
    int cp = (tid & 7) + ((tid >> 6) << 3);
    int rq = (tid >> 3) & 7;
    bool act = cp < 116;
    const u32* sp;
    int rstr;
    if (cp < 50)      { sp = t1b32 + cp;        rstr = 50; }
    else if (cp < 66) { sp = hb32 + (cp - 50);  rstr = 16; }
    else              { sp = s1b32 + (cp - 66); rstr = 50; }
    sp += (size_t)(nbase + rq * 4) * rstr;
    int step = rstr * 32;
    int doff = (2 * cp) * ZTS + rq * 4;

    if (tid < KP1) sRow[tid] = 0.f;
    if (tid < 3) sScal[tid] = 0.f;
    for (int i = tid; i < 32 * ZTS; i += 1024) {
        int r = 232 + i / ZTS, c = i % ZTS;
        sZ[0][r * ZTS + c] = 0; sZ[1][r * ZTS + c] = 0;
    }
    u32 a0, a1, a2, a3, b0 = 0, b1 = 0, b2 = 0, b3 = 0;
    if (act) {
        ld_cp(sp, rstr, a0, a1, a2, a3);
        st_cp(sZ[0], doff, a0, a1, a2, a3);
        sp += step;
        ld_cp(sp, rstr, b0, b1, b2, b3);
        sp += step;
    }
    __syncthreads();

    for (int nt = 0; nt < 16; nt += 2) {
        GRAM_MFMA(sZ[0]);
        if (act) {
            st_cp(sZ[1], doff, b0, b1, b2, b3);
            if (nt + 2 < 16) { ld_cp(sp, rstr, a0, a1, a2, a3); sp += step; }
        }
        __syncthreads();
        GRAM_MFMA(sZ[1]);
        if (act && nt + 2 < 16) {
            st_cp(sZ[0], doff, a0, a1, a2, a3);
            if (nt + 3 < 16) { ld_cp(sp, rstr, b0, b1, b2, b3); sp += step; }
        }
        __syncthreads();
    }
    // ---- two-phase dump into sC
    if (mfh == 0) {
        DUMP_TILE(acc00, 2 * mtb,     2 * ctb,     0)
        DUMP_TILE(acc01, 2 * mtb,     2 * ctb + 1, 0)
        DUMP_TILE(acc10, 2 * mtb + 1, 2 * ctb,     0)
        DUMP_TILE(acc11, 2 * mtb + 1, 2 * ctb + 1, 0)
    }
    __syncthreads();
    if (mfh == 1) {
        DUMP_TILE(acc00, 2 * mtb,     2 * ctb,     1)
        DUMP_TILE(acc01, 2 * mtb,     2 * ctb + 1, 1)
        DUMP_TILE(acc10, 2 * mtb + 1, 2 * ctb,     1)
        DUMP_TILE(acc11, 2 * mtb + 1, 2 * ctb + 1, 1)
    }
    __syncthreads();
    // ---- finalize sweep: row sums (minus diag), troa/trss/ssq (P1 stays in sC)
    {
        float ssq = 0.f, trss = 0.f, troa = 0.f;
        for (int idx = tid; idx < KP1 * 58; idx += 1024) {
            int k = idx / 58, q = idx - k * 58;
            float4 s = *(const float4*)&sC[k * 232 + q * 4];
            int c = q * 4;
            if (c < 100) {
                float rs = (s.x + s.y) + (s.z + s.w);
                if (k >= c && k < c + 4) { float d = ((const float*)&s)[k - c]; troa += d; rs -= d; }
                atomicAdd(&sRow[k], rs);
            } else if (c >= 132) {
                ssq += s.x * s.x + s.y * s.y + s.z * s.z + s.w * s.w;
                int l0 = c - 132;
                if (k >= l0 && k < l0 + 4) trss += ((const float*)&s)[k - l0];
            }
        }
#pragma unroll
        for (int off = 32; off >= 1; off >>= 1) {
            ssq  += __shfl_xor(ssq, off);
            trss += __shfl_xor(trss, off);
            troa += __shfl_xor(troa, off);
        }
        if ((tid & 63) == 0) {
            atomicAdd(&sScal[0], troa);
            atomicAdd(&sScal[1], trss);
            atomicAdd(&sScal[2], ssq);
        }
    }
    __syncthreads();
    if (tid == 0) {
        float o1 = sqrtf(fmaxf(2.f - 2.f * sScal[1] / (sqrtf(sScal[2]) * 10.f), 0.f));  // sqrt(K1)=10
        sL1 = -(sScal[0] / aux[g]) + o1;     // aux[g] = den1 (written by k_s1m)
    }
    if (tid < KP1) sd[tid] = sqrtf(sRow[tid]) + 1e-15f;
    __syncthreads();
    // ---- normalize A IN PLACE (cols 0..99, stride 232); stage x1p -> sXo
    for (int i = tid; i < KP1 * KP1; i += 1024) {
        int k = i / KP1, l = i - k * KP1;
        float v = sC[k * 232 + l];
        sC[k * 232 + l] = (k == l) ? 0.f : v / (sd[k] * sd[l]);
    }
    for (int i = tid; i < KP1 * HH; i += 1024) {
        int k = i >> 5, c = i & 31;
        sXo[i] = sC[k * 232 + 100 + c];
    }
    if (tid < 32) sG[tid] = 0.f;
    __syncthreads();

    // ================= stage 2 (from LDS) =================
    // y = A @ x1p at 800 threads (4 cols each); threads 800..1023 stage weights.
    int n8 = tid >> 3, cq8 = tid & 7;
    if (tid < 800) {
        float yv[4] = {0.f, 0.f, 0.f, 0.f};
        for (int mq = 0; mq < 25; mq++) {
            float4 a4 = *(const float4*)&sC[n8 * 232 + mq * 4];
            const float* xb = &sXo[(mq * 4) * HH + cq8 * 4];
            float aa[4] = {a4.x, a4.y, a4.z, a4.w};
#pragma unroll
            for (int mm = 0; mm < 4; mm++) {
                const float* xr = xb + mm * HH;
#pragma unroll
                for (int j = 0; j < 4; j++) yv[j] = fmaf(aa[mm], xr[j], yv[j]);
            }
        }
#pragma unroll
        for (int j = 0; j < 4; j++) sYo[n8 * HH + cq8 * 4 + j] = yv[j];
    } else {
        for (int i = tid - 800; i < 2048; i += 224) {
            if (i < 1024) swR[i] = relW[i];
            else          swQ[i - 1024] = rootW[i - 1024];
        }
    }
    __syncthreads();
    // x2 = relu(y @ relW + relB + x1p @ rootW) at 800 threads, weights from LDS
    float x2v[4];
    if (tid < 800) {
#pragma unroll
        for (int j = 0; j < 4; j++) x2v[j] = relB[cq8 * 4 + j];
        for (int j = 0; j < 32; j++) {
            float yj = sYo[n8 * HH + j];
            float xj = sXo[n8 * HH + j];
            const float* rw = &swR[j * 32 + cq8 * 4];
            const float* qw = &swQ[j * 32 + cq8 * 4];
#pragma unroll
            for (int jj = 0; jj < 4; jj++) x2v[jj] += yj * rw[jj] + xj * qw[jj];
        }
    }
    __syncthreads();
    if (tid < 800) {
#pragma unroll
        for (int j = 0; j < 4; j++) sXo[n8 * HH + cq8 * 4 + j] = fmaxf(x2v[j], 0.f);
    }
    __syncthreads();
    // s2 = softmax(x2 @ p2W + p2B); d2 and den2 partials
    if (tid < KP1) {
        float lg[10];
#pragma unroll
        for (int j = 0; j < 10; j++) lg[j] = p2B[j];
        for (int c = 0; c < 32; c++) {
            float xv = sXo[tid * HH + c];
#pragma unroll
            for (int j = 0; j < 10; j++) lg[j] = fmaf(xv, p2W[c * 10 + j], lg[j]);
        }
        float mx = lg[0];
#pragma unroll
        for (int j = 1; j < 10; j++) mx = fmaxf(mx, lg[j]);
        float se = 0.f;
#pragma unroll
        for (int j = 0; j < 10; j++) { lg[j] = __expf(lg[j] - mx); se += lg[j]; }
        float inv = 1.f / se, sq = 0.f;
#pragma unroll
        for (int j = 0; j < 10; j++) { float sv = lg[j] * inv; sS2[tid * 10 + j] = sv; sq += sv * sv; }
        float d2 = 0.f;
        for (int mq = 0; mq < 25; mq++) {
            float4 a4 = *(const float4*)&sC[tid * 232 + mq * 4];
            d2 += a4.x + a4.y + a4.z + a4.w;
        }
        red[tid] = d2 * sq;
    }
    __syncthreads();
    // t2 = A @ s2 ; P2 = s2^T x2 (kept in LDS)
    for (int p = tid; p < KP1 * KP2; p += 1024) {
        int n2 = p / 10, jj = p % 10;
        float a = 0.f;
        for (int m = 0; m < KP1; m++) a = fmaf(sC[n2 * 232 + m], sS2[m * 10 + jj], a);
        sT2[p] = a;
    }
    if (tid < KP2 * HH) {
        int k = tid >> 5, cc = tid & 31;
        float a = 0.f;
        for (int n2 = 0; n2 < KP1; n2++) a = fmaf(sS2[n2 * 10 + k], sXo[n2 * HH + cc], a);
        sP2[tid] = a;
    }
    __syncthreads();
    // oa2, ss2 at 500 threads: (pair, K-chunk of 20) partials, then combine
    if (tid < 500) {
        int pr = tid % 100, ch = tid / 100;
        int k = pr / 10, l = pr % 10;
        float oa = 0.f, ss = 0.f;
        int n0 = ch * 20;
        for (int n2 = n0; n2 < n0 + 20; n2++) {
            float sk = sS2[n2 * 10 + k];
            oa = fmaf(sk, sT2[n2 * 10 + l], oa);
            ss = fmaf(sk, sS2[n2 * 10 + l], ss);
        }
        oaP[tid] = oa; ssP[tid] = ss;
    }
    __syncthreads();
    if (tid < 100) {
        float oa = ((oaP[tid] + oaP[tid + 100]) + (oaP[tid + 200] + oaP[tid + 300])) + oaP[tid + 400];
        float ss = ((ssP[tid] + ssP[tid + 100]) + (ssP[tid + 200] + ssP[tid + 300])) + ssP[tid + 400];
        sA2[tid] = oa; sB2[tid] = ss;
    }
    __syncthreads();
    if (tid == 0) {
        float den2 = 0.f;
        for (int i = 0; i < 100; i++) den2 += red[i];
        float troa = 0.f, trss = 0.f, ssq = 0.f;
        for (int k = 0; k < 10; k++) { troa += sA2[k * 10 + k]; trss += sB2[k * 10 + k]; }
        for (int i = 0; i < 100; i++) ssq += sB2[i] * sB2[i];
        float o2 = sqrtf(fmaxf(2.f - 2.f * trss / (sqrtf(ssq) * 3.16227766f), 0.f)); // sqrt(10)
        float l2 = -(troa / den2) + o2;
        atomicAdd(&out[1280], (sL1 + l2) * (1.f / 128.f));   // fused k_loss
    }
    if (tid < 10) {
        float rs = 0.f;
        for (int l = 0; l < 10; l++) if (l != tid) rs += sA2[tid * 10 + l];
        sdd[tid] = sqrtf(rs) + 1e-15f;
    }
    __syncthreads();
    if (tid < 100) {
        int k = tid / 10, l = tid % 10;
        sAn[tid] = (k == l) ? 0.f : sA2[tid] / (sdd[k] * sdd[l]);
    }
    __syncthreads();
    // ---- conv3 + mean + MLP head + log_softmax
    if (tid < KP2 * HH) {
        int k = tid >> 5, cc = tid & 31;
        float a = 0.f;
#pragma unroll
        for (int m = 0; m < 10; m++) a = fmaf(sAn[k * 10 + m], sP2[m * HH + cc], a);
        sY3[tid] = a;
    }
    __syncthreads();
    if (tid < KP2 * HH) {
        int k = tid >> 5, cc = tid & 31;
        float v = relb3[cc];
        for (int j = 0; j < 32; j++)
            v += sY3[k * HH + j] * relW3[j * 32 + cc] + sP2[k * HH + j] * rootW3[j * 32 + cc];
        atomicAdd(&sG[cc], v * 0.1f);        // mean over 10 nodes
    }
    __syncthreads();
    if (tid < 32) {
        float v = l1b[tid];
        for (int j = 0; j < 32; j++) v = fmaf(sG[j], l1W[j * 32 + tid], v);
        sG1[tid] = fmaxf(v, 0.f);
    }
    __syncthreads();
    if (tid < 10) {
        float v = l2b[tid];
        for (int j = 0; j < 32; j++) v = fmaf(sG1[j], l2W[j * 10 + tid], v);
        sL[tid] = v;
    }
    __syncthreads();
    if (tid == 0) {
        float mx = sL[0];
        for (int j = 1; j < 10; j++) mx = fmaxf(mx, sL[j]);
        float se = 0.f;
        for (int j = 0; j < 10; j++) se += expf(sL[j] - mx);
        *sLse = mx + logf(se);
    }
    __syncthreads();
    if (tid < 10) out[(size_t)g * 10 + tid] = sL[tid] - *sLse;
}

extern "C" void kernel_launch(void* const* d_in, const int* in_sizes, int n_in,
                              void* d_out, int out_size, void* d_ws, size_t ws_size,
                              hipStream_t stream) {
    const float* x    = (const float*)d_in[0];
    const int*   ei   = (const int*)d_in[1];
    const float* c1W  = (const float*)d_in[3];
    const float* c1b  = (const float*)d_in[4];
    const float* p1W  = (const float*)d_in[5];
    const float* p1b  = (const float*)d_in[6];
    const float* relW2  = (const float*)d_in[7];
    const float* relb2  = (const float*)d_in[8];
    const float* rootW2 = (const float*)d_in[9];
    const float* p2W  = (const float*)d_in[10];
    const float* p2b  = (const float*)d_in[11];
    const float* relW3  = (const float*)d_in[12];
    const float* relb3  = (const float*)d_in[13];
    const float* rootW3 = (const float*)d_in[14];
    const float* l1W  = (const float*)d_in[15];
    const float* l1b  = (const float*)d_in[16];
    const float* l2W  = (const float*)d_in[17];
    const float* l2b  = (const float*)d_in[18];
    float* out = (float*)d_out;

    // ---- workspace layout
    int*  cnt_src = (int*)d_ws;                       // NT
    int*  cnt_dst = cnt_src + NT;                     // NT
    int*  off_src = cnt_dst + NT;                     // NT
    int*  off_dst = off_src + NT;                     // NT
    u16*  srt_dst = (u16*)(off_dst + NT);             // ET u16 (src-sorted, stores local dst)
    u16*  srt_src = srt_dst + ET;                     // ET u16 (dst-sorted, stores local src)
    float* dis = (float*)(srt_src + ET);              // NT
    u32*  xwb  = (u32*)(dis + NT);                    // NT*16 (bf16 x2)
    u32*  hb   = xwb + (size_t)NT * 16;               // NT*16
    u32*  s1b  = hb + (size_t)NT * 16;                // NT*50
    u32*  t1b  = s1b + (size_t)NT * 50;               // NT*50
    float* aux  = (float*)(t1b + (size_t)NT * 50);    // 128: den1

    k_pre<<<2 * TB, 1024, 0, stream>>>(ei, cnt_src, cnt_dst, off_src, off_dst,
                                       srt_dst, srt_src, dis, aux, x, c1W, (u16*)xwb, out);
    k_gcng<<<NT / 16, 256, 0, stream>>>(srt_src, off_dst, cnt_dst, xwb, dis, c1b, hb);
    k_s1m<<<NT / 128, 256, 0, stream>>>(hb, p1W, p1b, cnt_src, (u16*)s1b, aux /*den1*/);
    k_t1g<<<NT / 4, 256, 0, stream>>>(srt_dst, off_src, cnt_src, s1b, t1b);
    k_gram2<<<TB, 1024, 0, stream>>>(s1b, t1b, hb, aux, relW2, relb2, rootW2, p2W, p2b,
                                     relW3, relb3, rootW3, l1W, l1b, l2W, l2b, out);
}